// Round 12
// baseline (102.176 us; speedup 1.0000x reference)
//
#include <hip/hip_runtime.h>
#include <stdint.h>

// ---------------------------------------------------------------------------
// PPMI-GNN forward: 2-layer GCN with bf16-MFMA GEMMs and bf16 gathers.
//   h1b = bf16(x @ W1); a1b = bf16(relu(agg(h1b) + b1))
//   h2b = bf16(a1b @ W2); out = agg(h2b) + b2
// Round 12: no-zero slot table + no rec intermediate.
//   - slot table ent[dst*SLOTS + pos] is NEVER zero-initialized; agg reads
//     deg = min(cursor[dst], SLOTS) and masks the tail group (w=0, clamped
//     rows) -> garbage slots are never used; output deterministic.
//   - scatter decodes ei/nrm directly (no packed rec round-trip).
//   - prep0 = zero cursor + weight transpose only (~200KB).
// 5 launches: prep0 -> gemm1||pack+scatter -> agg1 -> gemm2 -> agg2.
// ---------------------------------------------------------------------------

typedef __attribute__((ext_vector_type(8))) short short8;   // 8 bf16
typedef __attribute__((ext_vector_type(4))) float f32x4;

#define SLOTS 48                 // slots per destination (multiple of 4)
#define OCAP  65536              // overflow list capacity

__device__ __forceinline__ unsigned short f2bf(float f) {   // RNE f32->bf16
    unsigned u = __float_as_uint(f);
    return (unsigned short)((u + 0x7FFFu + ((u >> 16) & 1u)) >> 16);
}
__device__ __forceinline__ float bf_lo(unsigned v) { return __uint_as_float(v << 16); }
__device__ __forceinline__ float bf_hi(unsigned v) { return __uint_as_float(v & 0xFFFF0000u); }
__device__ __forceinline__ float bf1(unsigned short v) { return __uint_as_float((unsigned)v << 16); }
__device__ __forceinline__ unsigned short f2h(float f) {
    _Float16 h = (_Float16)f;
    return __builtin_bit_cast(unsigned short, h);
}
__device__ __forceinline__ float h2f(unsigned u16) {
    _Float16 h = __builtin_bit_cast(_Float16, (unsigned short)(u16 & 0xFFFFu));
    return (float)h;
}

// ---- prep0: zero cursor/ocount + weight transpose (tiny) ------------------
__global__ __launch_bounds__(256) void k_prep0(int* __restrict__ cursor, int n,
                                               int* __restrict__ ocount,
                                               const float* __restrict__ W1,
                                               const float* __restrict__ W2,
                                               unsigned short* __restrict__ W1t,
                                               unsigned short* __restrict__ W2t,
                                               int FEAT, int HID, int EMB) {
    const int gid = blockIdx.x * blockDim.x + threadIdx.x;
    const int stride = gridDim.x * blockDim.x;
    if (gid == 0) *ocount = 0;
    int4* c4 = (int4*)cursor;
    const int n4 = n >> 2;
    for (int j = gid; j < n4; j += stride) c4[j] = make_int4(0, 0, 0, 0);
    for (int j = (n4 << 2) + gid; j < n; j += stride) cursor[j] = 0;
    const int t1 = FEAT * HID, t2 = HID * EMB;
    for (int i = gid; i < t1 + t2; i += stride) {
        if (i < t1) {
            int k = i / HID, nn = i % HID;
            W1t[(size_t)nn * FEAT + k] = f2bf(W1[i]);
        } else {
            int j = i - t1;
            int k = j / EMB, nn = j % EMB;
            W2t[(size_t)nn * HID + k] = f2bf(W2[j]);
        }
    }
}

// ---------------------------------------------------------------------------
// GEMM body: C[M,N] = A[M,K] @ Bt[N,K]^T, bf16 operands, f32 acc, BK=64.
// BM=64, 4 waves (2x2). LDS rows 128B, XOR-swizzled both sides (T2).
// ---------------------------------------------------------------------------
template <int BM, int BN, int FM, int FN, bool A_F32, bool OUT_BF16>
__device__ __forceinline__ void gemm_body(char* ldsA, char* ldsB,
                                          const void* __restrict__ Ag,
                                          const unsigned short* __restrict__ Bt,
                                          void* __restrict__ Cv,
                                          int M, int K, int N, int blk) {
    const int tid  = threadIdx.x;
    const int lane = tid & 63;
    const int wid  = tid >> 6;
    const int wr   = wid >> 1;
    const int wc   = wid & 1;
    const int m0   = blk * BM;

    f32x4 acc[FM][FN] = {};

    for (int k0 = 0; k0 < K; k0 += 64) {
        {
            const int row  = tid >> 2;        // BM==64
            const int kq   = tid & 3;         // 16 elems each
            const int grow = min(m0 + row, M - 1);
            const int kbb  = kq * 32;
            const int sw   = (row & 7) << 4;
            if (A_F32) {
                const float* src = (const float*)Ag + (size_t)grow * K + k0 + kq * 16;
                float4 v0 = ((const float4*)src)[0];
                float4 v1 = ((const float4*)src)[1];
                float4 v2 = ((const float4*)src)[2];
                float4 v3 = ((const float4*)src)[3];
                union { short8 s; unsigned short h[8]; } p0, p1;
                p0.h[0] = f2bf(v0.x); p0.h[1] = f2bf(v0.y);
                p0.h[2] = f2bf(v0.z); p0.h[3] = f2bf(v0.w);
                p0.h[4] = f2bf(v1.x); p0.h[5] = f2bf(v1.y);
                p0.h[6] = f2bf(v1.z); p0.h[7] = f2bf(v1.w);
                p1.h[0] = f2bf(v2.x); p1.h[1] = f2bf(v2.y);
                p1.h[2] = f2bf(v2.z); p1.h[3] = f2bf(v2.w);
                p1.h[4] = f2bf(v3.x); p1.h[5] = f2bf(v3.y);
                p1.h[6] = f2bf(v3.z); p1.h[7] = f2bf(v3.w);
                *(short8*)(ldsA + row * 128 + ( kbb       ^ sw)) = p0.s;
                *(short8*)(ldsA + row * 128 + ((kbb + 16) ^ sw)) = p1.s;
            } else {
                const unsigned short* src =
                    (const unsigned short*)Ag + (size_t)grow * K + k0 + kq * 16;
                short8 s0 = ((const short8*)src)[0];
                short8 s1 = ((const short8*)src)[1];
                *(short8*)(ldsA + row * 128 + ( kbb       ^ sw)) = s0;
                *(short8*)(ldsA + row * 128 + ((kbb + 16) ^ sw)) = s1;
            }
        }
        if (BN == 128 || tid < 128) {
            const int row = tid >> 1;
            const int kh  = tid & 1;
            const int sw  = (row & 7) << 4;
            const short8* src = (const short8*)(Bt + (size_t)row * K + k0 + kh * 32);
            #pragma unroll
            for (int j = 0; j < 4; ++j) {
                short8 s = src[j];
                int kb = kh * 64 + j * 16;
                *(short8*)(ldsB + row * 128 + (kb ^ sw)) = s;
            }
        }
        __syncthreads();

        #pragma unroll
        for (int s = 0; s < 2; ++s) {
            const int klo = s * 64 + (lane >> 4) * 16;
            short8 af[FM], bfv[FN];
            #pragma unroll
            for (int i = 0; i < FM; ++i) {
                int r = wr * (FM * 16) + i * 16 + (lane & 15);
                af[i] = *(const short8*)(ldsA + r * 128 + (klo ^ ((r & 7) << 4)));
            }
            #pragma unroll
            for (int j = 0; j < FN; ++j) {
                int n = wc * (FN * 16) + j * 16 + (lane & 15);
                bfv[j] = *(const short8*)(ldsB + n * 128 + (klo ^ ((n & 7) << 4)));
            }
            #pragma unroll
            for (int i = 0; i < FM; ++i)
                #pragma unroll
                for (int j = 0; j < FN; ++j)
                    acc[i][j] = __builtin_amdgcn_mfma_f32_16x16x32_bf16(
                        af[i], bfv[j], acc[i][j], 0, 0, 0);
        }
        __syncthreads();
    }

    // epilogue: C/D layout col=lane&15, row=(lane>>4)*4+reg
    #pragma unroll
    for (int i = 0; i < FM; ++i) {
        const int rbase = m0 + wr * (FM * 16) + i * 16 + ((lane >> 4) << 2);
        #pragma unroll
        for (int j = 0; j < FN; ++j) {
            const int c = wc * (FN * 16) + j * 16 + (lane & 15);
            #pragma unroll
            for (int r = 0; r < 4; ++r)
                if (rbase + r < M) {
                    if (OUT_BF16)
                        ((unsigned short*)Cv)[(size_t)(rbase + r) * N + c] = f2bf(acc[i][j][r]);
                    else
                        ((float*)Cv)[(size_t)(rbase + r) * N + c] = acc[i][j][r];
                }
        }
    }
}

template <int BM, int BN, int FM, int FN, bool A_F32, bool OUT_BF16>
__global__ __launch_bounds__(256) void k_gemm_mfma(const void* __restrict__ Ag,
                                                   const unsigned short* __restrict__ Bt,
                                                   void* __restrict__ Cv,
                                                   int M, int K, int N) {
    __shared__ char ldsA[BM * 128];
    __shared__ char ldsB[BN * 128];
    gemm_body<BM, BN, FM, FN, A_F32, OUT_BF16>(ldsA, ldsB, Ag, Bt, Cv, M, K, N,
                                               blockIdx.x);
}

// ---- fused: blocks [0,gemmBlocks) run gemm1; the rest pack+scatter --------
// Scatter decodes ei/nrm directly (per-block int64 ballot, int4 loads) and
// appends into the slot table via per-dst cursors. Disjoint writes vs gemm.
template <int BM, int BN, int FM, int FN, bool A_F32, bool OUT_BF16>
__global__ __launch_bounds__(256) void k_gemm_scatter(const void* __restrict__ Ag,
                                                      const unsigned short* __restrict__ Bt,
                                                      void* __restrict__ Cv,
                                                      int M, int K, int N,
                                                      int gemmBlocks,
                                                      const int* __restrict__ ei,
                                                      const float* __restrict__ nrm,
                                                      int E, int Nn,
                                                      int* __restrict__ cursor,
                                                      unsigned* __restrict__ ent,
                                                      uint2* __restrict__ olist,
                                                      int* __restrict__ ocount) {
    __shared__ char ldsA[BM * 128];
    __shared__ char ldsB[BN * 128];
    if ((int)blockIdx.x < gemmBlocks) {
        gemm_body<BM, BN, FM, FN, A_F32, OUT_BF16>(ldsA, ldsB, Ag, Bt, Cv, M, K, N,
                                                   blockIdx.x);
        return;
    }
    __shared__ int sIs64;
    if (threadIdx.x < 64) {                  // per-block int32/int64 detect
        const int i = 1 + 2 * threadIdx.x;
        int z = (i < 2 * E) ? (ei[i] == 0) : 1;
        unsigned long long m = __ballot(z);
        if (threadIdx.x == 0) sIs64 = (m == ~0ULL) ? 1 : 0;
    }
    __syncthreads();
    const int is64 = sIs64;

    const int t  = (blockIdx.x - gemmBlocks) * blockDim.x + threadIdx.x;
    const int e0 = t * 4;
    if (e0 >= E) return;

    int r[4], c[4];
    float wv[4];
    int nv = 4;
    if (e0 + 3 < E) {
        if (is64) {
            const int4* pr = (const int4*)(ei + 2 * e0);
            const int4* pc = (const int4*)(ei + 2 * E + 2 * e0);
            int4 r01 = pr[0], r23 = pr[1], c01 = pc[0], c23 = pc[1];
            r[0] = r01.x; r[1] = r01.z; r[2] = r23.x; r[3] = r23.z;
            c[0] = c01.x; c[1] = c01.z; c[2] = c23.x; c[3] = c23.z;
        } else {
            int4 rr = *(const int4*)(ei + e0);
            int4 cc = *(const int4*)(ei + E + e0);
            r[0] = rr.x; r[1] = rr.y; r[2] = rr.z; r[3] = rr.w;
            c[0] = cc.x; c[1] = cc.y; c[2] = cc.z; c[3] = cc.w;
        }
        const float4 w4 = *(const float4*)(nrm + e0);
        wv[0] = w4.x; wv[1] = w4.y; wv[2] = w4.z; wv[3] = w4.w;
    } else {
        nv = E - e0;
        for (int i = 0; i < nv; ++i) {
            const int e = e0 + i;
            if (is64) { r[i] = ei[2 * e]; c[i] = ei[2 * (E + e)]; }
            else      { r[i] = ei[e];     c[i] = ei[E + e]; }
            wv[i] = nrm[e];
        }
    }
    #pragma unroll
    for (int i = 0; i < 4; ++i) {
        if (i < nv && (unsigned)c[i] < (unsigned)Nn && (unsigned)r[i] < (unsigned)Nn) {
            const unsigned entry = ((unsigned)r[i] << 16) | (unsigned)f2h(wv[i]);
            const int pos = atomicAdd(&cursor[c[i]], 1);
            if (pos < SLOTS) ent[(size_t)c[i] * SLOTS + pos] = entry;
            else { int op = atomicAdd(ocount, 1);
                   if (op < OCAP) olist[op] = make_uint2((unsigned)c[i], entry); }
        }
    }
}

// ---------------------------------------------------------------------------
// Per-node gather-reduce over bf16 h: one wave per node, deg = min(cursor,
// SLOTS) groups of 4; tail group masked (w=0, rows clamped -> no NaN, no OOB).
// Overflow list scanned only if non-empty (uniform branch; expected 0).
// ---------------------------------------------------------------------------
template <int F, bool RELU, bool OUT_BF16>
__global__ __launch_bounds__(256) void k_agg(const unsigned short* __restrict__ h,
                                             const int* __restrict__ cursor,
                                             const unsigned* __restrict__ ent,
                                             const uint2* __restrict__ olist,
                                             const int* __restrict__ ocount,
                                             const float* __restrict__ bias,
                                             void* __restrict__ outp, int nnodes) {
    const int lane = threadIdx.x & 63;
    const int wid  = __builtin_amdgcn_readfirstlane(threadIdx.x >> 6);
    const int node = blockIdx.x * 4 + wid;
    if (node >= nnodes) return;
    const int deg = min(cursor[node], SLOTS);
    const unsigned* slots = ent + (size_t)node * SLOTS;
    const unsigned rmax = (unsigned)(nnodes - 1);

    if (F == 128) {
        const unsigned* hp = (const unsigned*)h;        // 64 x (2 bf16) per row
        float2 a0 = {0.f, 0.f}, a1 = {0.f, 0.f}, a2 = {0.f, 0.f}, a3 = {0.f, 0.f};
        for (int g = 0; g < deg; g += 4) {
            uint4 q = *(const uint4*)(slots + g);
            const int rem = deg - g;                    // >= 1
            float w0 = h2f(q.x), w1 = h2f(q.y), w2 = h2f(q.z), w3 = h2f(q.w);
            if (rem < 4) {                              // mask tail (wave-uniform)
                w1 = (rem > 1) ? w1 : 0.f;
                w2 = (rem > 2) ? w2 : 0.f;
                w3 = 0.f;                               // rem<4 => slot3 invalid
                if (rem == 3) w3 = 0.f; else if (rem > 3) {}
            }
            const unsigned v0 = hp[(size_t)min(q.x >> 16, rmax) * 64 + lane];
            const unsigned v1 = hp[(size_t)min(q.y >> 16, rmax) * 64 + lane];
            const unsigned v2 = hp[(size_t)min(q.z >> 16, rmax) * 64 + lane];
            const unsigned v3 = hp[(size_t)min(q.w >> 16, rmax) * 64 + lane];
            a0.x = fmaf(w0, bf_lo(v0), a0.x); a0.y = fmaf(w0, bf_hi(v0), a0.y);
            a1.x = fmaf(w1, bf_lo(v1), a1.x); a1.y = fmaf(w1, bf_hi(v1), a1.y);
            a2.x = fmaf(w2, bf_lo(v2), a2.x); a2.y = fmaf(w2, bf_hi(v2), a2.y);
            a3.x = fmaf(w3, bf_lo(v3), a3.x); a3.y = fmaf(w3, bf_hi(v3), a3.y);
        }
        float2 acc;
        acc.x = (a0.x + a1.x) + (a2.x + a3.x);
        acc.y = (a0.y + a1.y) + (a2.y + a3.y);
        const int oc = *ocount;                         // expected 0
        if (oc > 0) {
            for (int i = 0; i < oc && i < OCAP; ++i) {
                const uint2 it = olist[i];
                if ((int)it.x == node) {
                    const float w = h2f(it.y);
                    const unsigned v = hp[(size_t)min(it.y >> 16, rmax) * 64 + lane];
                    acc.x = fmaf(w, bf_lo(v), acc.x);
                    acc.y = fmaf(w, bf_hi(v), acc.y);
                }
            }
        }
        const float2 b = ((const float2*)bias)[lane];
        acc.x += b.x; acc.y += b.y;
        if (RELU) { acc.x = fmaxf(acc.x, 0.f); acc.y = fmaxf(acc.y, 0.f); }
        if (OUT_BF16) {
            unsigned pack = (unsigned)f2bf(acc.x) | ((unsigned)f2bf(acc.y) << 16);
            ((unsigned*)outp)[(size_t)node * 64 + lane] = pack;
        } else {
            ((float2*)outp)[(size_t)node * 64 + lane] = acc;
        }
    } else {  // F == 64: one ushort per lane
        float a0 = 0.f, a1 = 0.f, a2 = 0.f, a3 = 0.f;
        for (int g = 0; g < deg; g += 4) {
            uint4 q = *(const uint4*)(slots + g);
            const int rem = deg - g;
            float w0 = h2f(q.x), w1 = h2f(q.y), w2 = h2f(q.z), w3 = h2f(q.w);
            if (rem < 4) {
                w1 = (rem > 1) ? w1 : 0.f;
                w2 = (rem > 2) ? w2 : 0.f;
                w3 = 0.f;
            }
            const float f0 = bf1(h[(size_t)min(q.x >> 16, rmax) * 64 + lane]);
            const float f1 = bf1(h[(size_t)min(q.y >> 16, rmax) * 64 + lane]);
            const float f2 = bf1(h[(size_t)min(q.z >> 16, rmax) * 64 + lane]);
            const float f3 = bf1(h[(size_t)min(q.w >> 16, rmax) * 64 + lane]);
            a0 = fmaf(w0, f0, a0); a1 = fmaf(w1, f1, a1);
            a2 = fmaf(w2, f2, a2); a3 = fmaf(w3, f3, a3);
        }
        float acc = (a0 + a1) + (a2 + a3);
        const int oc = *ocount;
        if (oc > 0) {
            for (int i = 0; i < oc && i < OCAP; ++i) {
                const uint2 it = olist[i];
                if ((int)it.x == node)
                    acc = fmaf(h2f(it.y),
                               bf1(h[(size_t)min(it.y >> 16, rmax) * 64 + lane]), acc);
            }
        }
        acc += bias[lane];
        if (RELU) acc = fmaxf(acc, 0.f);
        ((float*)outp)[(size_t)node * 64 + lane] = acc;
    }
}

// ---------------------------------------------------------------------------

extern "C" void kernel_launch(void* const* d_in, const int* in_sizes, int n_in,
                              void* d_out, int out_size, void* d_ws, size_t ws_size,
                              hipStream_t stream) {
    const float* x   = (const float*)d_in[0];
    const int*   ei  = (const int*)d_in[1];
    const float* nrm = (const float*)d_in[2];
    const float* W1  = (const float*)d_in[3];
    const float* b1  = (const float*)d_in[4];
    const float* W2  = (const float*)d_in[5];
    const float* b2  = (const float*)d_in[6];
    float* out = (float*)d_out;

    const int HID  = in_sizes[4];            // 128
    const int FEAT = in_sizes[3] / HID;      // 256
    const int EMB  = in_sizes[5] / HID;      // 64
    const int Nn   = in_sizes[0] / FEAT;     // 50000  (< 65536: packed fmt ok)
    const int E    = in_sizes[2];            // 550000
    const int entWords = Nn * SLOTS;         // slot table size (u32), NOT zeroed

    char* p = (char*)d_ws;
    auto alloc = [&](size_t bytes) {
        char* r = p;
        p += (bytes + 255) & ~(size_t)255;
        return r;
    };
    unsigned short* h1b    = (unsigned short*)alloc((size_t)Nn * HID * 2);
    unsigned short* a1b    = (unsigned short*)alloc((size_t)Nn * HID * 2);
    unsigned short* h2b    = (unsigned short*)alloc((size_t)Nn * EMB * 2);
    unsigned short* W1t    = (unsigned short*)alloc((size_t)HID * FEAT * 2);
    unsigned short* W2t    = (unsigned short*)alloc((size_t)EMB * HID * 2);
    int*            cursor = (int*)           alloc((size_t)Nn * 4);
    unsigned*       ent    = (unsigned*)      alloc((size_t)entWords * 4 + 256);
    uint2*          olist  = (uint2*)         alloc((size_t)OCAP * 8);
    int*            ocount = (int*)           alloc(256);

    const int sctBlocks  = (E + 4 * 256 - 1) / (4 * 256);
    const int gemmBlocks = (Nn + 63) / 64;

    k_prep0<<<128, 256, 0, stream>>>(cursor, Nn, ocount,
                                     W1, W2, W1t, W2t, FEAT, HID, EMB);
    // pack+scatter || gemm1 (independent; disjoint writes)
    k_gemm_scatter<64, 128, 2, 4, true, true>
        <<<gemmBlocks + sctBlocks, 256, 0, stream>>>(
            (const void*)x, W1t, (void*)h1b, Nn, FEAT, HID,
            gemmBlocks, ei, nrm, E, Nn, cursor, ent, olist, ocount);

    k_agg<128, true, true><<<(Nn + 3) / 4, 256, 0, stream>>>(
        h1b, cursor, ent, olist, ocount, b1, (void*)a1b, Nn);

    k_gemm_mfma<64, 64, 2, 2, false, true><<<gemmBlocks, 256, 0, stream>>>(
        (const void*)a1b, W2t, (void*)h2b, Nn, HID, EMB);
    k_agg<64, false, false><<<(Nn + 3) / 4, 256, 0, stream>>>(
        h2b, cursor, ent, olist, ocount, b2, (void*)out, Nn);
}

// Round 13
// 92.281 us; speedup vs baseline: 1.1072x; 1.1072x over previous
//
#include <hip/hip_runtime.h>
#include <stdint.h>

// ---------------------------------------------------------------------------
// PPMI-GNN forward: 2-layer GCN with bf16-MFMA GEMMs and bf16 gathers.
//   h1b = bf16(x @ W1); a1b = bf16(relu(agg(h1b) + b1))
//   h2b = bf16(a1b @ W2); out = agg(h2b) + b2
// Round 13: XCD-local partitioned slot scatter.
//   - k_prep0: zero cursor + weight transpose + pack rec (a=(row<<16)|dst,
//     b=fp16(norm); invalid = 0xFFFFFFFF). One launch.
//   - fused kernel: blocks [0,gemmBlocks) = gemm1; rest = scatter with
//     partition = blockIdx&7 (same XCD under round-robin dispatch -> cursor
//     atomics + ent lines stay in ONE L2; no cross-XCD write ping-pong,
//     which was ~32MB of the 45MB WRITE_SIZE). Each partition re-reads the
//     4.4MB rec (8x total = +31MB streaming) - cheap vs the write-amp.
//     Correct for ANY block->XCD mapping (partition covers every dst once).
//   - agg: deg=min(cursor,SLOTS), tail-masked, no-zero ent (r12).
// 5 launches: prep0 -> gemm1||scatter -> agg1 -> gemm2 -> agg2.
// ---------------------------------------------------------------------------

typedef __attribute__((ext_vector_type(8))) short short8;   // 8 bf16
typedef __attribute__((ext_vector_type(4))) float f32x4;

#define SLOTS 48                 // slots per destination (multiple of 4)
#define OCAP  65536              // overflow list capacity

__device__ __forceinline__ unsigned short f2bf(float f) {   // RNE f32->bf16
    unsigned u = __float_as_uint(f);
    return (unsigned short)((u + 0x7FFFu + ((u >> 16) & 1u)) >> 16);
}
__device__ __forceinline__ float bf_lo(unsigned v) { return __uint_as_float(v << 16); }
__device__ __forceinline__ float bf_hi(unsigned v) { return __uint_as_float(v & 0xFFFF0000u); }
__device__ __forceinline__ float bf1(unsigned short v) { return __uint_as_float((unsigned)v << 16); }
__device__ __forceinline__ unsigned short f2h(float f) {
    _Float16 h = (_Float16)f;
    return __builtin_bit_cast(unsigned short, h);
}
__device__ __forceinline__ float h2f(unsigned u16) {
    _Float16 h = __builtin_bit_cast(_Float16, (unsigned short)(u16 & 0xFFFFu));
    return (float)h;
}

// ---- prep0: zero cursor/ocount + weight transpose + pack rec --------------
__global__ __launch_bounds__(256) void k_prep0(int* __restrict__ cursor, int n,
                                               int* __restrict__ ocount,
                                               const int* __restrict__ ei,
                                               const float* __restrict__ nrm,
                                               int E,
                                               unsigned* __restrict__ rec,
                                               const float* __restrict__ W1,
                                               const float* __restrict__ W2,
                                               unsigned short* __restrict__ W1t,
                                               unsigned short* __restrict__ W2t,
                                               int FEAT, int HID, int EMB) {
    __shared__ int sIs64;
    if (threadIdx.x < 64) {                  // per-block int32/int64 detect
        const int i = 1 + 2 * threadIdx.x;
        int z = (i < 2 * E) ? (ei[i] == 0) : 1;
        unsigned long long m = __ballot(z);
        if (threadIdx.x == 0) sIs64 = (m == ~0ULL) ? 1 : 0;
    }
    __syncthreads();
    const int is64 = sIs64;

    const int gid = blockIdx.x * blockDim.x + threadIdx.x;
    const int stride = gridDim.x * blockDim.x;
    if (gid == 0) *ocount = 0;

    int4* c4 = (int4*)cursor;
    const int n4 = n >> 2;
    for (int j = gid; j < n4; j += stride) c4[j] = make_int4(0, 0, 0, 0);
    for (int j = (n4 << 2) + gid; j < n; j += stride) cursor[j] = 0;

    const int t1 = FEAT * HID, t2 = HID * EMB;
    for (int i = gid; i < t1 + t2; i += stride) {
        if (i < t1) {
            int k = i / HID, nn = i % HID;
            W1t[(size_t)nn * FEAT + k] = f2bf(W1[i]);
        } else {
            int j = i - t1;
            int k = j / EMB, nn = j % EMB;
            W2t[(size_t)nn * HID + k] = f2bf(W2[j]);
        }
    }

    // pack edges: rec[2e]=(row<<16)|dst (0xFFFFFFFF invalid), rec[2e+1]=fp16(w)
    const int nG = (E + 3) / 4;
    for (int g = gid; g < nG; g += stride) {
        const int e0 = g * 4;
        if (e0 + 3 < E) {
            int r[4], c[4];
            if (is64) {
                const int4* pr = (const int4*)(ei + 2 * e0);
                const int4* pc = (const int4*)(ei + 2 * E + 2 * e0);
                int4 r01 = pr[0], r23 = pr[1], c01 = pc[0], c23 = pc[1];
                r[0] = r01.x; r[1] = r01.z; r[2] = r23.x; r[3] = r23.z;
                c[0] = c01.x; c[1] = c01.z; c[2] = c23.x; c[3] = c23.z;
            } else {
                int4 rr = *(const int4*)(ei + e0);
                int4 cc = *(const int4*)(ei + E + e0);
                r[0] = rr.x; r[1] = rr.y; r[2] = rr.z; r[3] = rr.w;
                c[0] = cc.x; c[1] = cc.y; c[2] = cc.z; c[3] = cc.w;
            }
            const float4 w4 = *(const float4*)(nrm + e0);
            const float wv[4] = {w4.x, w4.y, w4.z, w4.w};
            unsigned ow[8];
            #pragma unroll
            for (int i = 0; i < 4; ++i) {
                unsigned a = 0xFFFFFFFFu, b = 0u;
                if ((unsigned)c[i] < (unsigned)n && (unsigned)r[i] < (unsigned)n) {
                    a = ((unsigned)r[i] << 16) | (unsigned)c[i];
                    b = (unsigned)f2h(wv[i]);
                }
                ow[2 * i + 0] = a;
                ow[2 * i + 1] = b;
            }
            uint4* dst = (uint4*)(rec + 2 * (size_t)e0);
            dst[0] = make_uint4(ow[0], ow[1], ow[2], ow[3]);
            dst[1] = make_uint4(ow[4], ow[5], ow[6], ow[7]);
        } else {
            for (int i = 0; i < 4; ++i) {        // sanitize full tail group
                const int e = e0 + i;
                unsigned a = 0xFFFFFFFFu, b = 0u;
                if (e < E) {
                    int rr, cc;
                    if (is64) { rr = ei[2 * e]; cc = ei[2 * (E + e)]; }
                    else      { rr = ei[e];     cc = ei[E + e]; }
                    if ((unsigned)cc < (unsigned)n && (unsigned)rr < (unsigned)n) {
                        a = ((unsigned)rr << 16) | (unsigned)cc;
                        b = (unsigned)f2h(nrm[e]);
                    }
                }
                rec[2 * (size_t)e + 0] = a;
                rec[2 * (size_t)e + 1] = b;
            }
        }
    }
}

// ---------------------------------------------------------------------------
// GEMM body: C[M,N] = A[M,K] @ Bt[N,K]^T, bf16 operands, f32 acc, BK=64.
// BM=64, 4 waves (2x2). LDS rows 128B, XOR-swizzled both sides (T2).
// ---------------------------------------------------------------------------
template <int BM, int BN, int FM, int FN, bool A_F32, bool OUT_BF16>
__device__ __forceinline__ void gemm_body(char* ldsA, char* ldsB,
                                          const void* __restrict__ Ag,
                                          const unsigned short* __restrict__ Bt,
                                          void* __restrict__ Cv,
                                          int M, int K, int N, int blk) {
    const int tid  = threadIdx.x;
    const int lane = tid & 63;
    const int wid  = tid >> 6;
    const int wr   = wid >> 1;
    const int wc   = wid & 1;
    const int m0   = blk * BM;

    f32x4 acc[FM][FN] = {};

    for (int k0 = 0; k0 < K; k0 += 64) {
        {
            const int row  = tid >> 2;        // BM==64
            const int kq   = tid & 3;         // 16 elems each
            const int grow = min(m0 + row, M - 1);
            const int kbb  = kq * 32;
            const int sw   = (row & 7) << 4;
            if (A_F32) {
                const float* src = (const float*)Ag + (size_t)grow * K + k0 + kq * 16;
                float4 v0 = ((const float4*)src)[0];
                float4 v1 = ((const float4*)src)[1];
                float4 v2 = ((const float4*)src)[2];
                float4 v3 = ((const float4*)src)[3];
                union { short8 s; unsigned short h[8]; } p0, p1;
                p0.h[0] = f2bf(v0.x); p0.h[1] = f2bf(v0.y);
                p0.h[2] = f2bf(v0.z); p0.h[3] = f2bf(v0.w);
                p0.h[4] = f2bf(v1.x); p0.h[5] = f2bf(v1.y);
                p0.h[6] = f2bf(v1.z); p0.h[7] = f2bf(v1.w);
                p1.h[0] = f2bf(v2.x); p1.h[1] = f2bf(v2.y);
                p1.h[2] = f2bf(v2.z); p1.h[3] = f2bf(v2.w);
                p1.h[4] = f2bf(v3.x); p1.h[5] = f2bf(v3.y);
                p1.h[6] = f2bf(v3.z); p1.h[7] = f2bf(v3.w);
                *(short8*)(ldsA + row * 128 + ( kbb       ^ sw)) = p0.s;
                *(short8*)(ldsA + row * 128 + ((kbb + 16) ^ sw)) = p1.s;
            } else {
                const unsigned short* src =
                    (const unsigned short*)Ag + (size_t)grow * K + k0 + kq * 16;
                short8 s0 = ((const short8*)src)[0];
                short8 s1 = ((const short8*)src)[1];
                *(short8*)(ldsA + row * 128 + ( kbb       ^ sw)) = s0;
                *(short8*)(ldsA + row * 128 + ((kbb + 16) ^ sw)) = s1;
            }
        }
        if (BN == 128 || tid < 128) {
            const int row = tid >> 1;
            const int kh  = tid & 1;
            const int sw  = (row & 7) << 4;
            const short8* src = (const short8*)(Bt + (size_t)row * K + k0 + kh * 32);
            #pragma unroll
            for (int j = 0; j < 4; ++j) {
                short8 s = src[j];
                int kb = kh * 64 + j * 16;
                *(short8*)(ldsB + row * 128 + (kb ^ sw)) = s;
            }
        }
        __syncthreads();

        #pragma unroll
        for (int s = 0; s < 2; ++s) {
            const int klo = s * 64 + (lane >> 4) * 16;
            short8 af[FM], bfv[FN];
            #pragma unroll
            for (int i = 0; i < FM; ++i) {
                int r = wr * (FM * 16) + i * 16 + (lane & 15);
                af[i] = *(const short8*)(ldsA + r * 128 + (klo ^ ((r & 7) << 4)));
            }
            #pragma unroll
            for (int j = 0; j < FN; ++j) {
                int n = wc * (FN * 16) + j * 16 + (lane & 15);
                bfv[j] = *(const short8*)(ldsB + n * 128 + (klo ^ ((n & 7) << 4)));
            }
            #pragma unroll
            for (int i = 0; i < FM; ++i)
                #pragma unroll
                for (int j = 0; j < FN; ++j)
                    acc[i][j] = __builtin_amdgcn_mfma_f32_16x16x32_bf16(
                        af[i], bfv[j], acc[i][j], 0, 0, 0);
        }
        __syncthreads();
    }

    // epilogue: C/D layout col=lane&15, row=(lane>>4)*4+reg
    #pragma unroll
    for (int i = 0; i < FM; ++i) {
        const int rbase = m0 + wr * (FM * 16) + i * 16 + ((lane >> 4) << 2);
        #pragma unroll
        for (int j = 0; j < FN; ++j) {
            const int c = wc * (FN * 16) + j * 16 + (lane & 15);
            #pragma unroll
            for (int r = 0; r < 4; ++r)
                if (rbase + r < M) {
                    if (OUT_BF16)
                        ((unsigned short*)Cv)[(size_t)(rbase + r) * N + c] = f2bf(acc[i][j][r]);
                    else
                        ((float*)Cv)[(size_t)(rbase + r) * N + c] = acc[i][j][r];
                }
        }
    }
}

template <int BM, int BN, int FM, int FN, bool A_F32, bool OUT_BF16>
__global__ __launch_bounds__(256) void k_gemm_mfma(const void* __restrict__ Ag,
                                                   const unsigned short* __restrict__ Bt,
                                                   void* __restrict__ Cv,
                                                   int M, int K, int N) {
    __shared__ char ldsA[BM * 128];
    __shared__ char ldsB[BN * 128];
    gemm_body<BM, BN, FM, FN, A_F32, OUT_BF16>(ldsA, ldsB, Ag, Bt, Cv, M, K, N,
                                               blockIdx.x);
}

// ---- fused: blocks [0,gemmBlocks) = gemm1; rest = PARTITIONED scatter -----
// partition = blockIdx&7 (absolute residue -> one XCD under round-robin
// dispatch); slice = (blockIdx-gemmBlocks)>>3. Residues of consecutive
// scatter blocks cycle mod 8, so (partition, slice) covers every pair exactly
// once when sctBlocks % 8 == 0. Correct for ANY mapping; fast when residue
// pins XCD (cursor atomics + ent lines stay in one L2).
template <int BM, int BN, int FM, int FN, bool A_F32, bool OUT_BF16, int PAIRS>
__global__ __launch_bounds__(256) void k_gemm_scatter(const void* __restrict__ Ag,
                                                      const unsigned short* __restrict__ Bt,
                                                      void* __restrict__ Cv,
                                                      int M, int K, int N,
                                                      int gemmBlocks,
                                                      const uint4* __restrict__ rec4,
                                                      int nPairs, int Nn,
                                                      int* __restrict__ cursor,
                                                      unsigned* __restrict__ ent,
                                                      uint2* __restrict__ olist,
                                                      int* __restrict__ ocount) {
    __shared__ char ldsA[BM * 128];
    __shared__ char ldsB[BN * 128];
    if ((int)blockIdx.x < gemmBlocks) {
        gemm_body<BM, BN, FM, FN, A_F32, OUT_BF16>(ldsA, ldsB, Ag, Bt, Cv, M, K, N,
                                                   blockIdx.x);
        return;
    }
    const int part  = blockIdx.x & 7;
    const int slice = (blockIdx.x - gemmBlocks) >> 3;
    const int np    = (Nn + 7) / 8;
    const unsigned lo = (unsigned)(part * np);
    const unsigned hi = (unsigned)min(Nn, (int)lo + np);

    const int base = slice * (256 * PAIRS) + threadIdx.x;
    #pragma unroll
    for (int j = 0; j < PAIRS; ++j) {
        const int p = base + j * 256;
        if (p < nPairs) {
            const uint4 q = rec4[p];
            if (q.x != 0xFFFFFFFFu) {
                const unsigned d = q.x & 0xFFFFu;
                if (d >= lo && d < hi) {
                    const unsigned entry = (q.x & 0xFFFF0000u) | q.y;
                    const int pos = atomicAdd(&cursor[d], 1);
                    if (pos < SLOTS) ent[(size_t)d * SLOTS + pos] = entry;
                    else { int op = atomicAdd(ocount, 1);
                           if (op < OCAP) olist[op] = make_uint2(d, entry); }
                }
            }
            if (q.z != 0xFFFFFFFFu) {
                const unsigned d = q.z & 0xFFFFu;
                if (d >= lo && d < hi) {
                    const unsigned entry = (q.z & 0xFFFF0000u) | q.w;
                    const int pos = atomicAdd(&cursor[d], 1);
                    if (pos < SLOTS) ent[(size_t)d * SLOTS + pos] = entry;
                    else { int op = atomicAdd(ocount, 1);
                           if (op < OCAP) olist[op] = make_uint2(d, entry); }
                }
            }
        }
    }
}

// ---------------------------------------------------------------------------
// Per-node gather-reduce over bf16 h: one wave per node, deg = min(cursor,
// SLOTS) groups of 4; tail group masked (w=0, rows clamped -> no NaN, no OOB).
// Overflow list scanned only if non-empty (uniform branch; expected 0).
// ---------------------------------------------------------------------------
template <int F, bool RELU, bool OUT_BF16>
__global__ __launch_bounds__(256) void k_agg(const unsigned short* __restrict__ h,
                                             const int* __restrict__ cursor,
                                             const unsigned* __restrict__ ent,
                                             const uint2* __restrict__ olist,
                                             const int* __restrict__ ocount,
                                             const float* __restrict__ bias,
                                             void* __restrict__ outp, int nnodes) {
    const int lane = threadIdx.x & 63;
    const int wid  = __builtin_amdgcn_readfirstlane(threadIdx.x >> 6);
    const int node = blockIdx.x * 4 + wid;
    if (node >= nnodes) return;
    const int deg = min(cursor[node], SLOTS);
    const unsigned* slots = ent + (size_t)node * SLOTS;
    const unsigned rmax = (unsigned)(nnodes - 1);

    if (F == 128) {
        const unsigned* hp = (const unsigned*)h;        // 64 x (2 bf16) per row
        float2 a0 = {0.f, 0.f}, a1 = {0.f, 0.f}, a2 = {0.f, 0.f}, a3 = {0.f, 0.f};
        for (int g = 0; g < deg; g += 4) {
            uint4 q = *(const uint4*)(slots + g);
            const int rem = deg - g;                    // >= 1
            float w0 = h2f(q.x), w1 = h2f(q.y), w2 = h2f(q.z), w3 = h2f(q.w);
            if (rem < 4) {                              // mask tail (wave-uniform)
                w1 = (rem > 1) ? w1 : 0.f;
                w2 = (rem > 2) ? w2 : 0.f;
                w3 = 0.f;
            }
            const unsigned v0 = hp[(size_t)min(q.x >> 16, rmax) * 64 + lane];
            const unsigned v1 = hp[(size_t)min(q.y >> 16, rmax) * 64 + lane];
            const unsigned v2 = hp[(size_t)min(q.z >> 16, rmax) * 64 + lane];
            const unsigned v3 = hp[(size_t)min(q.w >> 16, rmax) * 64 + lane];
            a0.x = fmaf(w0, bf_lo(v0), a0.x); a0.y = fmaf(w0, bf_hi(v0), a0.y);
            a1.x = fmaf(w1, bf_lo(v1), a1.x); a1.y = fmaf(w1, bf_hi(v1), a1.y);
            a2.x = fmaf(w2, bf_lo(v2), a2.x); a2.y = fmaf(w2, bf_hi(v2), a2.y);
            a3.x = fmaf(w3, bf_lo(v3), a3.x); a3.y = fmaf(w3, bf_hi(v3), a3.y);
        }
        float2 acc;
        acc.x = (a0.x + a1.x) + (a2.x + a3.x);
        acc.y = (a0.y + a1.y) + (a2.y + a3.y);
        const int oc = *ocount;                         // expected 0
        if (oc > 0) {
            for (int i = 0; i < oc && i < OCAP; ++i) {
                const uint2 it = olist[i];
                if ((int)it.x == node) {
                    const float w = h2f(it.y);
                    const unsigned v = hp[(size_t)min(it.y >> 16, rmax) * 64 + lane];
                    acc.x = fmaf(w, bf_lo(v), acc.x);
                    acc.y = fmaf(w, bf_hi(v), acc.y);
                }
            }
        }
        const float2 b = ((const float2*)bias)[lane];
        acc.x += b.x; acc.y += b.y;
        if (RELU) { acc.x = fmaxf(acc.x, 0.f); acc.y = fmaxf(acc.y, 0.f); }
        if (OUT_BF16) {
            unsigned pack = (unsigned)f2bf(acc.x) | ((unsigned)f2bf(acc.y) << 16);
            ((unsigned*)outp)[(size_t)node * 64 + lane] = pack;
        } else {
            ((float2*)outp)[(size_t)node * 64 + lane] = acc;
        }
    } else {  // F == 64: one ushort per lane
        float a0 = 0.f, a1 = 0.f, a2 = 0.f, a3 = 0.f;
        for (int g = 0; g < deg; g += 4) {
            uint4 q = *(const uint4*)(slots + g);
            const int rem = deg - g;
            float w0 = h2f(q.x), w1 = h2f(q.y), w2 = h2f(q.z), w3 = h2f(q.w);
            if (rem < 4) {
                w1 = (rem > 1) ? w1 : 0.f;
                w2 = (rem > 2) ? w2 : 0.f;
                w3 = 0.f;
            }
            const float f0 = bf1(h[(size_t)min(q.x >> 16, rmax) * 64 + lane]);
            const float f1 = bf1(h[(size_t)min(q.y >> 16, rmax) * 64 + lane]);
            const float f2 = bf1(h[(size_t)min(q.z >> 16, rmax) * 64 + lane]);
            const float f3 = bf1(h[(size_t)min(q.w >> 16, rmax) * 64 + lane]);
            a0 = fmaf(w0, f0, a0); a1 = fmaf(w1, f1, a1);
            a2 = fmaf(w2, f2, a2); a3 = fmaf(w3, f3, a3);
        }
        float acc = (a0 + a1) + (a2 + a3);
        const int oc = *ocount;
        if (oc > 0) {
            for (int i = 0; i < oc && i < OCAP; ++i) {
                const uint2 it = olist[i];
                if ((int)it.x == node)
                    acc = fmaf(h2f(it.y),
                               bf1(h[(size_t)min(it.y >> 16, rmax) * 64 + lane]), acc);
            }
        }
        acc += bias[lane];
        if (RELU) acc = fmaxf(acc, 0.f);
        ((float*)outp)[(size_t)node * 64 + lane] = acc;
    }
}

// ---------------------------------------------------------------------------

extern "C" void kernel_launch(void* const* d_in, const int* in_sizes, int n_in,
                              void* d_out, int out_size, void* d_ws, size_t ws_size,
                              hipStream_t stream) {
    const float* x   = (const float*)d_in[0];
    const int*   ei  = (const int*)d_in[1];
    const float* nrm = (const float*)d_in[2];
    const float* W1  = (const float*)d_in[3];
    const float* b1  = (const float*)d_in[4];
    const float* W2  = (const float*)d_in[5];
    const float* b2  = (const float*)d_in[6];
    float* out = (float*)d_out;

    const int HID  = in_sizes[4];            // 128
    const int FEAT = in_sizes[3] / HID;      // 256
    const int EMB  = in_sizes[5] / HID;      // 64
    const int Nn   = in_sizes[0] / FEAT;     // 50000  (< 65536: packed fmt ok)
    const int E    = in_sizes[2];            // 550000
    const int E4   = (E + 3) & ~3;           // rec length (4-group sanitized)
    const int entWords = Nn * SLOTS;         // slot table (u32), NOT zeroed

    char* p = (char*)d_ws;
    auto alloc = [&](size_t bytes) {
        char* r = p;
        p += (bytes + 255) & ~(size_t)255;
        return r;
    };
    unsigned short* h1b    = (unsigned short*)alloc((size_t)Nn * HID * 2);
    unsigned short* a1b    = (unsigned short*)alloc((size_t)Nn * HID * 2);
    unsigned short* h2b    = (unsigned short*)alloc((size_t)Nn * EMB * 2);
    unsigned short* W1t    = (unsigned short*)alloc((size_t)HID * FEAT * 2);
    unsigned short* W2t    = (unsigned short*)alloc((size_t)EMB * HID * 2);
    int*            cursor = (int*)           alloc((size_t)Nn * 4);
    unsigned*       ent    = (unsigned*)      alloc((size_t)entWords * 4 + 256);
    unsigned*       rec    = (unsigned*)      alloc((size_t)E4 * 8);
    uint2*          olist  = (uint2*)         alloc((size_t)OCAP * 8);
    int*            ocount = (int*)           alloc(256);

    constexpr int PAIRS  = 2;                 // uint4 pairs per thread
    const int nPairs     = E4 / 2;            // uint4 count in rec
    const int sctSlices  = (nPairs + 256 * PAIRS - 1) / (256 * PAIRS);
    const int sctBlocks  = sctSlices * 8;     // 8 partitions
    const int gemmBlocks = (Nn + 63) / 64;

    k_prep0<<<1024, 256, 0, stream>>>(cursor, Nn, ocount, ei, nrm, E, rec,
                                      W1, W2, W1t, W2t, FEAT, HID, EMB);
    // partitioned scatter || gemm1 (independent; disjoint writes)
    k_gemm_scatter<64, 128, 2, 4, true, true, PAIRS>
        <<<gemmBlocks + sctBlocks, 256, 0, stream>>>(
            (const void*)x, W1t, (void*)h1b, Nn, FEAT, HID,
            gemmBlocks, (const uint4*)rec, nPairs, Nn, cursor, ent, olist, ocount);

    k_agg<128, true, true><<<(Nn + 3) / 4, 256, 0, stream>>>(
        h1b, cursor, ent, olist, ocount, b1, (void*)a1b, Nn);

    k_gemm_mfma<64, 64, 2, 2, false, true><<<gemmBlocks, 256, 0, stream>>>(
        (const void*)a1b, W2t, (void*)h2b, Nn, HID, EMB);
    k_agg<64, false, false><<<(Nn + 3) / 4, 256, 0, stream>>>(
        h2b, cursor, ent, olist, ocount, b2, (void*)out, Nn);
}